// Round 1
// baseline (3546.725 us; speedup 1.0000x reference)
//
#include <hip/hip_runtime.h>
#include <hip/hip_bf16.h>
#include <cstdint>

#define DEV static __device__ __forceinline__

DEV uint32_t bf16rne(float f) {
    uint32_t u = __float_as_uint(f);
    uint32_t r = u + 0x7FFFu + ((u >> 16) & 1u);
    return r >> 16;
}
DEV float bf16tof(uint32_t h) { return __uint_as_float((h & 0xFFFFu) << 16); }
DEV float hsig(float z) { return fminf(fmaxf(0.2f * z + 0.5f, 0.f), 1.f); }
DEV float lrelu(float x) { return x >= 0.f ? x : 0.3f * x; }

#define HH 82
#define WW 67
#define PIX (HH * WW)   // 5494
#define BB 64
#define TT 24

// ---------------- Kernel 1: xz = conv(x_t, wx) + b_lstm for all t, bf16x4 packed ----------------
__global__ __launch_bounds__(256) void k_xz(
    const float* __restrict__ inp, const float* __restrict__ wx,
    const float* __restrict__ bl, uint2* __restrict__ xz)
{
    int p = blockIdx.x * 256 + threadIdx.x;
    const int NP = BB * TT * PIX;
    if (p >= NP) return;
    int x = p % WW;
    int y = (p / WW) % HH;
    int bt = p / PIX;
    float g0 = bl[0], g1 = bl[1], g2 = bl[2], g3 = bl[3];
    #pragma unroll
    for (int ky = 0; ky < 3; ++ky) {
        int iy = y + ky - 1;
        if (iy < 0 || iy >= HH) continue;
        #pragma unroll
        for (int kx = 0; kx < 3; ++kx) {
            int ix = x + kx - 1;
            if (ix < 0 || ix >= WW) continue;
            const float* ib = inp + ((size_t)bt * PIX + iy * WW + ix) * 6;
            const float* wb = wx + (ky * 3 + kx) * 24;
            #pragma unroll
            for (int ci = 0; ci < 6; ++ci) {
                float v = ib[ci];
                g0 += v * wb[ci * 4 + 0];
                g1 += v * wb[ci * 4 + 1];
                g2 += v * wb[ci * 4 + 2];
                g3 += v * wb[ci * 4 + 3];
            }
        }
    }
    uint32_t lo = bf16rne(g0) | (bf16rne(g1) << 16);
    uint32_t hi = bf16rne(g2) | (bf16rne(g3) << 16);
    xz[p] = make_uint2(lo, hi);
}

// ---------------- Kernel 2: sequential LSTM, one block per batch image ----------------
__global__ __launch_bounds__(1024) void k_lstm(
    const uint2* __restrict__ xz, const float* __restrict__ wh,
    float* __restrict__ hout)
{
    __shared__ float hb[2][PIX];
    int b = blockIdx.x;
    int tid = threadIdx.x;
    float whr[9][4];
    #pragma unroll
    for (int k = 0; k < 9; ++k)
        #pragma unroll
        for (int g = 0; g < 4; ++g) whr[k][g] = wh[k * 4 + g];
    float cr[6];
    #pragma unroll
    for (int i = 0; i < 6; ++i) {
        int p = tid + i * 1024;
        if (p < PIX) { hb[0][p] = 0.f; }
        cr[i] = 0.f;
    }
    __syncthreads();
    #pragma unroll 1
    for (int t = 0; t < TT; ++t) {
        int cur = t & 1;
        const uint2* zb = xz + ((size_t)b * TT + t) * PIX;
        #pragma unroll
        for (int i = 0; i < 6; ++i) {
            int p = tid + i * 1024;
            if (p >= PIX) break;
            int x = p % WW, y = p / WW;
            uint2 zp = zb[p];
            float z0 = bf16tof(zp.x), z1 = bf16tof(zp.x >> 16);
            float z2 = bf16tof(zp.y), z3 = bf16tof(zp.y >> 16);
            #pragma unroll
            for (int ky = 0; ky < 3; ++ky) {
                int iy = y + ky - 1;
                if (iy < 0 || iy >= HH) continue;
                #pragma unroll
                for (int kx = 0; kx < 3; ++kx) {
                    int ix = x + kx - 1;
                    if (ix < 0 || ix >= WW) continue;
                    float hv = hb[cur][iy * WW + ix];
                    z0 += hv * whr[ky * 3 + kx][0];
                    z1 += hv * whr[ky * 3 + kx][1];
                    z2 += hv * whr[ky * 3 + kx][2];
                    z3 += hv * whr[ky * 3 + kx][3];
                }
            }
            float fi = hsig(z0), ff = hsig(z1), fo = hsig(z3);
            float cn = ff * cr[i] + fi * tanhf(z2);
            cr[i] = cn;
            hb[cur ^ 1][p] = fo * tanhf(cn);
        }
        __syncthreads();
    }
    #pragma unroll
    for (int i = 0; i < 6; ++i) {
        int p = tid + i * 1024;
        if (p < PIX) hout[(size_t)b * PIX + p] = hb[0][p];
    }
}

// ---------------- Kernel 3: conv1 5x5 s2 SAME, 6->64, +bias, LeakyReLU ----------------
// out x1: [64,41,34,64]; wave per (b,y), lane = co
__global__ __launch_bounds__(256) void k_conv1(
    const float* __restrict__ hin, const float* __restrict__ tar,
    const float* __restrict__ w1, const float* __restrict__ b1,
    float* __restrict__ out)
{
    int wid = (blockIdx.x * 256 + threadIdx.x) >> 6;
    int lane = threadIdx.x & 63;
    int b = wid / 41, y = wid % 41;
    float acc[34];
    float bias = b1[lane];
    #pragma unroll
    for (int x = 0; x < 34; ++x) acc[x] = bias;
    #pragma unroll 1
    for (int ky = 0; ky < 5; ++ky) {
        int iy = 2 * y + ky - 1;
        if (iy < 0 || iy >= HH) continue;
        const float* hrow = hin + (size_t)b * PIX + iy * WW;
        const float* trow = tar + ((size_t)b * PIX + iy * WW) * 5;
        #pragma unroll 1
        for (int kx = 0; kx < 5; ++kx) {
            float w[6];
            #pragma unroll
            for (int ci = 0; ci < 6; ++ci)
                w[ci] = w1[((ky * 5 + kx) * 6 + ci) * 64 + lane];
            #pragma unroll
            for (int x = 0; x < 34; ++x) {
                int ix = 2 * x + kx - 2;
                if (ix < 0 || ix >= WW) continue;
                float v0 = hrow[ix];
                acc[x] += v0 * w[0];
                #pragma unroll
                for (int c = 0; c < 5; ++c)
                    acc[x] += trow[ix * 5 + c] * w[c + 1];
            }
        }
    }
    float* orow = out + (size_t)(b * 41 + y) * 34 * 64;
    #pragma unroll
    for (int x = 0; x < 34; ++x)
        orow[x * 64 + lane] = lrelu(acc[x]);
}

// ---------------- Kernel 4: conv2 5x5 s2 SAME, 64->128, +bias, LeakyReLU ----------------
// out x2: [64,21,17,128]; wave per (b,y,coh), lane->co
__global__ __launch_bounds__(256) void k_conv2(
    const float* __restrict__ x1, const float* __restrict__ w2,
    const float* __restrict__ b2, float* __restrict__ out)
{
    int wid = (blockIdx.x * 256 + threadIdx.x) >> 6;
    int lane = threadIdx.x & 63;
    int b = wid / 42;
    int rem = wid % 42;
    int y = rem >> 1;
    int co = (rem & 1) * 64 + lane;
    float acc[17];
    float bias = b2[co];
    #pragma unroll
    for (int x = 0; x < 17; ++x) acc[x] = bias;
    #pragma unroll 1
    for (int ky = 0; ky < 5; ++ky) {
        int iy = 2 * y + ky - 2;
        if (iy < 0 || iy >= 41) continue;
        #pragma unroll 1
        for (int kx = 0; kx < 5; ++kx) {
            #pragma unroll 1
            for (int c4 = 0; c4 < 16; ++c4) {
                float wa = w2[((ky * 5 + kx) * 64 + c4 * 4 + 0) * 128 + co];
                float wb = w2[((ky * 5 + kx) * 64 + c4 * 4 + 1) * 128 + co];
                float wc = w2[((ky * 5 + kx) * 64 + c4 * 4 + 2) * 128 + co];
                float wd = w2[((ky * 5 + kx) * 64 + c4 * 4 + 3) * 128 + co];
                #pragma unroll
                for (int x = 0; x < 17; ++x) {
                    int ix = 2 * x + kx - 1;
                    if (ix < 0 || ix >= 34) continue;
                    const float4 v = *(const float4*)(x1 + ((size_t)(b * 41 + iy) * 34 + ix) * 64 + c4 * 4);
                    acc[x] += v.x * wa + v.y * wb + v.z * wc + v.w * wd;
                }
            }
        }
    }
    float* orow = out + (size_t)(b * 21 + y) * 17 * 128;
    #pragma unroll
    for (int x = 0; x < 17; ++x)
        orow[x * 128 + co] = lrelu(acc[x]);
}

// ---------------- Kernel 5: pad1 + conv3 4x4 VALID, 128->512, BN, LeakyReLU ----------------
// out x3: [64,20,16,512]; wave per (b,y,cog), lane->co
__global__ __launch_bounds__(256) void k_conv3(
    const float* __restrict__ x2, const float* __restrict__ w3,
    const float* __restrict__ gam, const float* __restrict__ bet,
    const float* __restrict__ mean, const float* __restrict__ var,
    float* __restrict__ out)
{
    int wid = (blockIdx.x * 256 + threadIdx.x) >> 6;
    int lane = threadIdx.x & 63;
    int b = wid / 160;
    int rem = wid % 160;
    int y = rem / 8;
    int co = (rem % 8) * 64 + lane;
    float acc[16];
    #pragma unroll
    for (int x = 0; x < 16; ++x) acc[x] = 0.f;
    #pragma unroll 1
    for (int ky = 0; ky < 4; ++ky) {
        int iy = y + ky - 1;
        if (iy < 0 || iy >= 21) continue;
        #pragma unroll 1
        for (int kx = 0; kx < 4; ++kx) {
            #pragma unroll 1
            for (int c4 = 0; c4 < 32; ++c4) {
                float wa = w3[((ky * 4 + kx) * 128 + c4 * 4 + 0) * 512 + co];
                float wb = w3[((ky * 4 + kx) * 128 + c4 * 4 + 1) * 512 + co];
                float wc = w3[((ky * 4 + kx) * 128 + c4 * 4 + 2) * 512 + co];
                float wd = w3[((ky * 4 + kx) * 128 + c4 * 4 + 3) * 512 + co];
                #pragma unroll
                for (int x = 0; x < 16; ++x) {
                    int ix = x + kx - 1;
                    if (ix < 0 || ix >= 17) continue;
                    const float4 v = *(const float4*)(x2 + ((size_t)(b * 21 + iy) * 17 + ix) * 128 + c4 * 4);
                    acc[x] += v.x * wa + v.y * wb + v.z * wc + v.w * wd;
                }
            }
        }
    }
    float scale = gam[co] * rsqrtf(var[co] + 1e-3f);
    float shift = bet[co] - mean[co] * scale;
    float* orow = out + (size_t)(b * 20 + y) * 16 * 512;
    #pragma unroll
    for (int x = 0; x < 16; ++x)
        orow[x * 512 + co] = lrelu(acc[x] * scale + shift);
}

// ---------------- Kernel 6: pad1 + conv4 4x4 VALID, 512->1, +bias ----------------
// out: [64,19,15]; one wave per (b,y), lanes split ci, shuffle-reduce
__global__ __launch_bounds__(64) void k_conv4(
    const float* __restrict__ x3, const float* __restrict__ w4,
    const float* __restrict__ b4, float* __restrict__ out)
{
    int b = blockIdx.x / 19, y = blockIdx.x % 19;
    int lane = threadIdx.x;
    float acc[15];
    #pragma unroll
    for (int x = 0; x < 15; ++x) acc[x] = 0.f;
    #pragma unroll 1
    for (int ky = 0; ky < 4; ++ky) {
        int iy = y + ky - 1;
        if (iy < 0 || iy >= 20) continue;
        #pragma unroll 1
        for (int kx = 0; kx < 4; ++kx) {
            #pragma unroll 1
            for (int c8 = 0; c8 < 8; ++c8) {
                int ci = c8 * 64 + lane;
                float w = w4[(ky * 4 + kx) * 512 + ci];
                #pragma unroll
                for (int x = 0; x < 15; ++x) {
                    int ix = x + kx - 1;
                    if (ix < 0 || ix >= 16) continue;
                    acc[x] += x3[((size_t)(b * 20 + iy) * 16 + ix) * 512 + ci] * w;
                }
            }
        }
    }
    float bias = b4[0];
    #pragma unroll
    for (int x = 0; x < 15; ++x) {
        float s = acc[x];
        #pragma unroll
        for (int off = 32; off > 0; off >>= 1)
            s += __shfl_down(s, off);
        if (lane == 0) out[(size_t)blockIdx.x * 15 + x] = s + bias;
    }
}

extern "C" void kernel_launch(void* const* d_in, const int* in_sizes, int n_in,
                              void* d_out, int out_size, void* d_ws, size_t ws_size,
                              hipStream_t stream)
{
    const float* inp  = (const float*)d_in[0];
    const float* tar  = (const float*)d_in[1];
    const float* wx   = (const float*)d_in[2];
    const float* wh   = (const float*)d_in[3];
    const float* bl   = (const float*)d_in[4];
    const float* w1   = (const float*)d_in[5];
    const float* b1   = (const float*)d_in[6];
    const float* w2   = (const float*)d_in[7];
    const float* b2   = (const float*)d_in[8];
    const float* w3   = (const float*)d_in[9];
    const float* gam  = (const float*)d_in[10];
    const float* bet  = (const float*)d_in[11];
    const float* mean = (const float*)d_in[12];
    const float* var  = (const float*)d_in[13];
    const float* w4   = (const float*)d_in[14];
    const float* b4   = (const float*)d_in[15];
    float* out = (float*)d_out;

    char* ws = (char*)d_ws;
    // xz: [64,24,5494] x 4 gates bf16 = 67,510,272 B  (dead after k_lstm)
    // x3 aliases xz (41,943,040 B), used by conv3->conv4
    uint2* xz   = (uint2*)(ws);
    float* x3   = (float*)(ws);
    float* hfin = (float*)(ws + 67510272);   // 1,406,464 B
    float* x1   = (float*)(ws + 68916736);   // 22,839,296 B
    float* x2   = (float*)(ws + 91756032);   // 11,698,176 B -> total ~103.5 MB

    const int NP = BB * TT * PIX;
    k_xz<<<(NP + 255) / 256, 256, 0, stream>>>(inp, wx, bl, xz);
    k_lstm<<<BB, 1024, 0, stream>>>(xz, wh, hfin);
    k_conv1<<<656, 256, 0, stream>>>(hfin, tar, w1, b1, x1);    // 2624 waves
    k_conv2<<<672, 256, 0, stream>>>(x1, w2, b2, x2);           // 2688 waves
    k_conv3<<<2560, 256, 0, stream>>>(x2, w3, gam, bet, mean, var, x3); // 10240 waves
    k_conv4<<<BB * 19, 64, 0, stream>>>(x3, w4, b4, out);
}

// Round 2
// 595.815 us; speedup vs baseline: 5.9527x; 5.9527x over previous
//
#include <hip/hip_runtime.h>
#include <hip/hip_bf16.h>
#include <cstdint>

#define DEV static __device__ __forceinline__

typedef __attribute__((ext_vector_type(8))) short short8;
typedef __attribute__((ext_vector_type(4))) float f32x4;

DEV uint32_t bf16rne(float f) {
    uint32_t u = __float_as_uint(f);
    uint32_t r = u + 0x7FFFu + ((u >> 16) & 1u);
    return r >> 16;
}
DEV float bf16tof(uint32_t h) { return __uint_as_float((h & 0xFFFFu) << 16); }
DEV float hsig(float z) { return fminf(fmaxf(0.2f * z + 0.5f, 0.f), 1.f); }
DEV float lrelu(float x) { return x >= 0.f ? x : 0.3f * x; }

DEV void gload16(const void* g, void* l) {
    __builtin_amdgcn_global_load_lds(
        reinterpret_cast<const __attribute__((address_space(1))) uint32_t*>(
            reinterpret_cast<uintptr_t>(g)),
        reinterpret_cast<__attribute__((address_space(3))) uint32_t*>(
            reinterpret_cast<uintptr_t>(l)),
        16, 0, 0);
}

#define HH 82
#define WW 67
#define PIX (HH * WW)   // 5494
#define BB 64
#define TT 24

// ---------------- Kernel 1: xz = conv(x_t, wx) + b_lstm for all t, bf16x4 packed ----------------
__global__ __launch_bounds__(256) void k_xz(
    const float* __restrict__ inp, const float* __restrict__ wx,
    const float* __restrict__ bl, uint2* __restrict__ xz)
{
    int p = blockIdx.x * 256 + threadIdx.x;
    const int NP = BB * TT * PIX;
    if (p >= NP) return;
    int x = p % WW;
    int y = (p / WW) % HH;
    int bt = p / PIX;
    float g0 = bl[0], g1 = bl[1], g2 = bl[2], g3 = bl[3];
    #pragma unroll
    for (int ky = 0; ky < 3; ++ky) {
        int iy = y + ky - 1;
        if (iy < 0 || iy >= HH) continue;
        #pragma unroll
        for (int kx = 0; kx < 3; ++kx) {
            int ix = x + kx - 1;
            if (ix < 0 || ix >= WW) continue;
            const float* ib = inp + ((size_t)bt * PIX + iy * WW + ix) * 6;
            const float* wb = wx + (ky * 3 + kx) * 24;
            #pragma unroll
            for (int ci = 0; ci < 6; ++ci) {
                float v = ib[ci];
                g0 += v * wb[ci * 4 + 0];
                g1 += v * wb[ci * 4 + 1];
                g2 += v * wb[ci * 4 + 2];
                g3 += v * wb[ci * 4 + 3];
            }
        }
    }
    uint32_t lo = bf16rne(g0) | (bf16rne(g1) << 16);
    uint32_t hi = bf16rne(g2) | (bf16rne(g3) << 16);
    xz[p] = make_uint2(lo, hi);
}

// ---------------- Kernel 2: sequential LSTM, one block per batch image ----------------
__global__ __launch_bounds__(1024) void k_lstm(
    const uint2* __restrict__ xz, const float* __restrict__ wh,
    float* __restrict__ hout)
{
    __shared__ float hb[2][PIX];
    int b = blockIdx.x;
    int tid = threadIdx.x;
    float whr[9][4];
    #pragma unroll
    for (int k = 0; k < 9; ++k)
        #pragma unroll
        for (int g = 0; g < 4; ++g) whr[k][g] = wh[k * 4 + g];
    float cr[6];
    #pragma unroll
    for (int i = 0; i < 6; ++i) {
        int p = tid + i * 1024;
        if (p < PIX) { hb[0][p] = 0.f; }
        cr[i] = 0.f;
    }
    __syncthreads();
    #pragma unroll 1
    for (int t = 0; t < TT; ++t) {
        int cur = t & 1;
        const uint2* zb = xz + ((size_t)b * TT + t) * PIX;
        #pragma unroll
        for (int i = 0; i < 6; ++i) {
            int p = tid + i * 1024;
            if (p >= PIX) break;
            int x = p % WW, y = p / WW;
            uint2 zp = zb[p];
            float z0 = bf16tof(zp.x), z1 = bf16tof(zp.x >> 16);
            float z2 = bf16tof(zp.y), z3 = bf16tof(zp.y >> 16);
            #pragma unroll
            for (int ky = 0; ky < 3; ++ky) {
                int iy = y + ky - 1;
                if (iy < 0 || iy >= HH) continue;
                #pragma unroll
                for (int kx = 0; kx < 3; ++kx) {
                    int ix = x + kx - 1;
                    if (ix < 0 || ix >= WW) continue;
                    float hv = hb[cur][iy * WW + ix];
                    z0 += hv * whr[ky * 3 + kx][0];
                    z1 += hv * whr[ky * 3 + kx][1];
                    z2 += hv * whr[ky * 3 + kx][2];
                    z3 += hv * whr[ky * 3 + kx][3];
                }
            }
            float fi = hsig(z0), ff = hsig(z1), fo = hsig(z3);
            float cn = ff * cr[i] + fi * tanhf(z2);
            cr[i] = cn;
            hb[cur ^ 1][p] = fo * tanhf(cn);
        }
        __syncthreads();
    }
    #pragma unroll
    for (int i = 0; i < 6; ++i) {
        int p = tid + i * 1024;
        if (p < PIX) hout[(size_t)b * PIX + p] = hb[0][p];
    }
}

// ---------------- Kernel 3: conv1 5x5 s2 SAME, 6->64, +bias, LeakyReLU ----------------
// writes bf16 into padded x1p[64][45][37][64] at (y+2, x+1)
__global__ __launch_bounds__(256) void k_conv1(
    const float* __restrict__ hin, const float* __restrict__ tar,
    const float* __restrict__ w1, const float* __restrict__ b1,
    ushort* __restrict__ x1p)
{
    int wid = (blockIdx.x * 256 + threadIdx.x) >> 6;
    int lane = threadIdx.x & 63;
    int b = wid / 41, y = wid % 41;
    float acc[34];
    float bias = b1[lane];
    #pragma unroll
    for (int x = 0; x < 34; ++x) acc[x] = bias;
    #pragma unroll 1
    for (int ky = 0; ky < 5; ++ky) {
        int iy = 2 * y + ky - 1;
        if (iy < 0 || iy >= HH) continue;
        const float* hrow = hin + (size_t)b * PIX + iy * WW;
        const float* trow = tar + ((size_t)b * PIX + iy * WW) * 5;
        #pragma unroll 1
        for (int kx = 0; kx < 5; ++kx) {
            float w[6];
            #pragma unroll
            for (int ci = 0; ci < 6; ++ci)
                w[ci] = w1[((ky * 5 + kx) * 6 + ci) * 64 + lane];
            #pragma unroll
            for (int x = 0; x < 34; ++x) {
                int ix = 2 * x + kx - 2;
                if (ix < 0 || ix >= WW) continue;
                float v0 = hrow[ix];
                acc[x] += v0 * w[0];
                #pragma unroll
                for (int c = 0; c < 5; ++c)
                    acc[x] += trow[ix * 5 + c] * w[c + 1];
            }
        }
    }
    ushort* obase = x1p + ((size_t)(b * 45 + y + 2) * 37) * 64;
    #pragma unroll
    for (int x = 0; x < 34; ++x)
        obase[(x + 1) * 64 + lane] = (ushort)bf16rne(lrelu(acc[x]));
}

// ---------------- Weight transpose+cvt: wt[n][k] = bf16(w[k][n]) ----------------
__global__ __launch_bounds__(256) void k_wt(
    const float* __restrict__ w, ushort* __restrict__ wt, int K, int N)
{
    int idx = blockIdx.x * 256 + threadIdx.x;
    if (idx >= K * N) return;
    int n = idx / K, k = idx % K;
    wt[idx] = (ushort)bf16rne(w[(size_t)k * N + n]);
}

// ---------------- MFMA implicit-GEMM conv (conv2 / conv3) ----------------
// IS3=true : conv3  A=x2p[64][23][19][128], B=w3t[512][2048], out fp32 x3 + BN + lrelu
// IS3=false: conv2  A=x1p[64][45][37][64],  B=w2t[128][1600], out bf16 into x2p(+1,+1) + bias + lrelu
template<bool IS3>
__global__ __launch_bounds__(256) void k_convm(
    const ushort* __restrict__ Ain, const ushort* __restrict__ Bt,
    const float* __restrict__ p0, const float* __restrict__ p1,
    const float* __restrict__ p2, const float* __restrict__ p3,
    float* __restrict__ out_f32, ushort* __restrict__ out_bf16)
{
    constexpr int OH = IS3 ? 20 : 21, OW = IS3 ? 16 : 17;
    constexpr int PH = IS3 ? 23 : 45, PW = IS3 ? 19 : 37;
    constexpr int CIN = IS3 ? 128 : 64;
    constexpr int KW_ = IS3 ? 4 : 5;
    constexpr int KK  = IS3 ? 16 : 25;     // kernel positions
    constexpr int STR = IS3 ? 1 : 2;
    constexpr int HALVES = CIN / 64;
    constexpr int MPB = OH * OW;
    constexpr int M = 64 * MPB;
    constexpr int KTOT = KK * CIN;

    __shared__ ushort At[128 * 64];
    __shared__ ushort Bl[128 * 64];

    const int tid = threadIdx.x;
    const int wid = tid >> 6, lane = tid & 63;
    const int m0 = blockIdx.x * 128;
    const int n0 = blockIdx.y * 128;
    const int wr = wid >> 1, wc = wid & 1;

    // pre-swizzled per-lane k-chunk offset (elements) for staging source
    const int swz = (((lane & 7) ^ ((lane >> 3) & 7)) << 3);

    // per-lane A source row bases (element offsets), 4 staging instrs per wave
    int arow_base[4], brow_base[4];
    #pragma unroll
    for (int i = 0; i < 4; ++i) {
        int row = wid * 32 + i * 8 + (lane >> 3);
        int m = m0 + row; if (m > M - 1) m = M - 1;
        int b = m / MPB, r = m % MPB;
        int y = r / OW, x = r % OW;
        arow_base[i] = ((b * PH + y * STR) * PW + x * STR) * CIN;
        brow_base[i] = (n0 + row) * KTOT;
    }

    f32x4 acc[4][4];
    #pragma unroll
    for (int i = 0; i < 4; ++i)
        #pragma unroll
        for (int j = 0; j < 4; ++j) acc[i][j] = (f32x4){0.f, 0.f, 0.f, 0.f};

    #pragma unroll 1
    for (int kp = 0; kp < KK; ++kp) {
        const int ky = kp / KW_, kx = kp % KW_;
        const int aoff = (ky * PW + kx) * CIN;
        #pragma unroll
        for (int h = 0; h < HALVES; ++h) {
            const int koff = h * 64;
            #pragma unroll
            for (int i = 0; i < 4; ++i) {
                gload16(Ain + arow_base[i] + aoff + koff + swz,
                        (void*)(At + (wid * 32 + i * 8) * 64));
                gload16(Bt + brow_base[i] + kp * CIN + koff + swz,
                        (void*)(Bl + (wid * 32 + i * 8) * 64));
            }
            __syncthreads();
            #pragma unroll
            for (int ks = 0; ks < 2; ++ks) {
                short8 af[4], bf[4];
                const int lc = ks * 64 + ((lane >> 4) << 4);  // logical byte col in row
                #pragma unroll
                for (int mf = 0; mf < 4; ++mf) {
                    int row = wr * 64 + mf * 16 + (lane & 15);
                    af[mf] = *(const short8*)((const char*)At + row * 128 + (lc ^ ((row & 7) << 4)));
                }
                #pragma unroll
                for (int nf = 0; nf < 4; ++nf) {
                    int row = wc * 64 + nf * 16 + (lane & 15);
                    bf[nf] = *(const short8*)((const char*)Bl + row * 128 + (lc ^ ((row & 7) << 4)));
                }
                #pragma unroll
                for (int mf = 0; mf < 4; ++mf)
                    #pragma unroll
                    for (int nf = 0; nf < 4; ++nf)
                        acc[mf][nf] = __builtin_amdgcn_mfma_f32_16x16x32_bf16(
                            af[mf], bf[nf], acc[mf][nf], 0, 0, 0);
            }
            __syncthreads();
        }
    }

    // epilogue
    if (IS3) {
        #pragma unroll
        for (int nf = 0; nf < 4; ++nf) {
            int n = n0 + wc * 64 + nf * 16 + (lane & 15);
            float sc = p0[n] * rsqrtf(p3[n] + 1e-3f);      // gamma * rsqrt(var+eps)
            float sh = p1[n] - p2[n] * sc;                 // beta - mean*scale
            #pragma unroll
            for (int mf = 0; mf < 4; ++mf) {
                int mbase = m0 + wr * 64 + mf * 16 + ((lane >> 4) << 2);
                #pragma unroll
                for (int r = 0; r < 4; ++r) {
                    float v = lrelu(acc[mf][nf][r] * sc + sh);
                    out_f32[(size_t)(mbase + r) * 512 + n] = v;
                }
            }
        }
    } else {
        #pragma unroll
        for (int nf = 0; nf < 4; ++nf) {
            int n = wc * 64 + nf * 16 + (lane & 15);
            float bias = p0[n];
            #pragma unroll
            for (int mf = 0; mf < 4; ++mf) {
                int mbase = m0 + wr * 64 + mf * 16 + ((lane >> 4) << 2);
                #pragma unroll
                for (int r = 0; r < 4; ++r) {
                    int m = mbase + r;
                    if (m < M) {
                        int b = m / MPB, rr = m % MPB;
                        int y = rr / OW, x = rr % OW;
                        float v = lrelu(acc[mf][nf][r] + bias);
                        out_bf16[((size_t)((b * 23) + (y + 1)) * 19 + (x + 1)) * 128 + n] =
                            (ushort)bf16rne(v);
                    }
                }
            }
        }
    }
}

// ---------------- Kernel 6: pad1 + conv4 4x4 VALID, 512->1, +bias ----------------
__global__ __launch_bounds__(64) void k_conv4(
    const float* __restrict__ x3, const float* __restrict__ w4,
    const float* __restrict__ b4, float* __restrict__ out)
{
    int b = blockIdx.x / 19, y = blockIdx.x % 19;
    int lane = threadIdx.x;
    float acc[15];
    #pragma unroll
    for (int x = 0; x < 15; ++x) acc[x] = 0.f;
    #pragma unroll 1
    for (int ky = 0; ky < 4; ++ky) {
        int iy = y + ky - 1;
        if (iy < 0 || iy >= 20) continue;
        #pragma unroll 1
        for (int kx = 0; kx < 4; ++kx) {
            #pragma unroll 1
            for (int c8 = 0; c8 < 8; ++c8) {
                int ci = c8 * 64 + lane;
                float w = w4[(ky * 4 + kx) * 512 + ci];
                #pragma unroll
                for (int x = 0; x < 15; ++x) {
                    int ix = x + kx - 1;
                    if (ix < 0 || ix >= 16) continue;
                    acc[x] += x3[((size_t)(b * 20 + iy) * 16 + ix) * 512 + ci] * w;
                }
            }
        }
    }
    float bias = b4[0];
    #pragma unroll
    for (int x = 0; x < 15; ++x) {
        float s = acc[x];
        #pragma unroll
        for (int off = 32; off > 0; off >>= 1)
            s += __shfl_down(s, off);
        if (lane == 0) out[(size_t)blockIdx.x * 15 + x] = s + bias;
    }
}

extern "C" void kernel_launch(void* const* d_in, const int* in_sizes, int n_in,
                              void* d_out, int out_size, void* d_ws, size_t ws_size,
                              hipStream_t stream)
{
    const float* inp  = (const float*)d_in[0];
    const float* tar  = (const float*)d_in[1];
    const float* wx   = (const float*)d_in[2];
    const float* wh   = (const float*)d_in[3];
    const float* bl   = (const float*)d_in[4];
    const float* w1   = (const float*)d_in[5];
    const float* b1   = (const float*)d_in[6];
    const float* w2   = (const float*)d_in[7];
    const float* b2   = (const float*)d_in[8];
    const float* w3   = (const float*)d_in[9];
    const float* gam  = (const float*)d_in[10];
    const float* bet  = (const float*)d_in[11];
    const float* mean = (const float*)d_in[12];
    const float* var  = (const float*)d_in[13];
    const float* w4   = (const float*)d_in[14];
    const float* b4   = (const float*)d_in[15];
    float* out = (float*)d_out;

    char* ws = (char*)d_ws;
    // xz: 67,510,272 B (dead after k_lstm); x3 fp32 41,943,040 B aliases it
    uint2*  xz   = (uint2*)(ws);
    float*  x3   = (float*)(ws);
    float*  hfin = (float*)(ws + 67510272);     // 1,406,464 B
    ushort* x1p  = (ushort*)(ws + 68916736);    // 64*45*37*64 bf16 = 13,639,680 B
    ushort* x2p  = (ushort*)(ws + 82556416);    // 64*23*19*128 bf16 = 7,159,808 B
    ushort* w2t  = (ushort*)(ws + 89716224);    // 128*1600 bf16 = 409,600 B
    ushort* w3t  = (ushort*)(ws + 90125824);    // 512*2048 bf16 = 2,097,152 B
    // total 92,222,976 B

    hipMemsetAsync(x1p, 0, 13639680, stream);
    hipMemsetAsync(x2p, 0, 7159808, stream);

    k_wt<<<(128 * 1600 + 255) / 256, 256, 0, stream>>>(w2, w2t, 1600, 128);
    k_wt<<<(512 * 2048 + 255) / 256, 256, 0, stream>>>(w3, w3t, 2048, 512);

    const int NP = BB * TT * PIX;
    k_xz<<<(NP + 255) / 256, 256, 0, stream>>>(inp, wx, bl, xz);
    k_lstm<<<BB, 1024, 0, stream>>>(xz, wh, hfin);
    k_conv1<<<656, 256, 0, stream>>>(hfin, tar, w1, b1, x1p);

    // conv2: M=22848 -> 179 tiles, N=128 -> 1 tile
    dim3 g2(179, 1);
    k_convm<false><<<g2, 256, 0, stream>>>(x1p, w2t, b2, nullptr, nullptr, nullptr,
                                           nullptr, x2p);
    // conv3: M=20480 -> 160 tiles, N=512 -> 4 tiles
    dim3 g3(160, 4);
    k_convm<true><<<g3, 256, 0, stream>>>(x2p, w3t, gam, bet, mean, var, x3, nullptr);

    k_conv4<<<BB * 19, 64, 0, stream>>>(x3, w4, b4, out);
}

// Round 3
// 574.752 us; speedup vs baseline: 6.1709x; 1.0366x over previous
//
#include <hip/hip_runtime.h>
#include <hip/hip_bf16.h>
#include <cstdint>

#define DEV static __device__ __forceinline__

typedef __attribute__((ext_vector_type(8))) short short8;
typedef __attribute__((ext_vector_type(4))) float f32x4;

DEV uint32_t bf16rne(float f) {
    uint32_t u = __float_as_uint(f);
    uint32_t r = u + 0x7FFFu + ((u >> 16) & 1u);
    return r >> 16;
}
DEV float bf16tof(uint32_t h) { return __uint_as_float((h & 0xFFFFu) << 16); }
DEV float hsig(float z) { return fminf(fmaxf(0.2f * z + 0.5f, 0.f), 1.f); }
DEV float lrelu(float x) { return x >= 0.f ? x : 0.3f * x; }
DEV float ftanh(float x) {
    // tanh(x) = 1 - 2/(e^{2x}+1); saturates correctly at +-inf
    float e = __expf(2.0f * x);
    return 1.0f - 2.0f * __builtin_amdgcn_rcpf(e + 1.0f);
}

DEV void gload16(const void* g, void* l) {
    __builtin_amdgcn_global_load_lds(
        reinterpret_cast<const __attribute__((address_space(1))) uint32_t*>(
            reinterpret_cast<uintptr_t>(g)),
        reinterpret_cast<__attribute__((address_space(3))) uint32_t*>(
            reinterpret_cast<uintptr_t>(l)),
        16, 0, 0);
}

#define HH 82
#define WW 67
#define PIX (HH * WW)   // 5494
#define BB 64
#define TT 24

// ---------------- Kernel 1: xz = conv(x_t, wx) + b_lstm, LDS-tiled ----------------
// grid: (bt=1536) x (strip=6); block 256. Strip = 14 output rows, 16 staged rows.
// LDS x-layout permuted: sigma(x) = (x&3)*17 + (x>>2), row stride 408 floats.
__global__ __launch_bounds__(256) void k_xz(
    const float* __restrict__ inp, const float* __restrict__ wx,
    const float* __restrict__ bl, uint2* __restrict__ xz)
{
    __shared__ float s[16 * 408];
    const int blk = blockIdx.x;
    const int bt = blk / 6, strip = blk % 6;
    const int r0 = strip * 14;
    const int nrows = (r0 + 14 <= HH) ? 14 : (HH - r0);   // 14 or 12
    const float* img = inp + (size_t)bt * (PIX * 6);
    const int tid = threadIdx.x;

    // stage rows r0-1 .. r0+14 (16 rows) as float2, x-permuted
    for (int i = tid; i < 16 * 201; i += 256) {
        int lr = i / 201, i2 = i % 201;
        int px = i2 / 3, c2 = i2 % 3;
        int gr = r0 - 1 + lr;
        float2 v = make_float2(0.f, 0.f);
        if (gr >= 0 && gr < HH)
            v = *(const float2*)(img + (size_t)gr * 402 + i2 * 2);
        int sig = (px & 3) * 17 + (px >> 2);
        *(float2*)(s + lr * 408 + sig * 6 + c2 * 2) = v;
    }
    __syncthreads();

    const int run = tid;
    if (run < nrows * 17) {
        const int ry = run / 17, x0 = (run % 17) * 4;
        float acc[4][4];
        #pragma unroll
        for (int xo = 0; xo < 4; ++xo)
            #pragma unroll
            for (int g = 0; g < 4; ++g) acc[xo][g] = bl[g];

        #pragma unroll
        for (int ky = 0; ky < 3; ++ky) {
            const float* wk = wx + ky * 72;
            const float* row = s + (ry + ky) * 408;
            #pragma unroll
            for (int dx = -1; dx < 5; ++dx) {
                int xi = x0 + dx;
                if (xi < 0 || xi >= WW) continue;
                int sig = (xi & 3) * 17 + (xi >> 2);
                const float* pp = row + sig * 6;
                float2 p0 = *(const float2*)(pp);
                float2 p1 = *(const float2*)(pp + 2);
                float2 p2 = *(const float2*)(pp + 4);
                float v[6] = {p0.x, p0.y, p1.x, p1.y, p2.x, p2.y};
                #pragma unroll
                for (int kx = 0; kx < 3; ++kx) {
                    int xo = dx - kx + 1;
                    if (xo < 0 || xo > 3) continue;
                    const float* w6 = wk + kx * 24;
                    #pragma unroll
                    for (int ci = 0; ci < 6; ++ci)
                        #pragma unroll
                        for (int g = 0; g < 4; ++g)
                            acc[xo][g] = fmaf(v[ci], w6[ci * 4 + g], acc[xo][g]);
                }
            }
        }
        const int y = r0 + ry;
        uint2* orow = xz + ((size_t)bt * HH + y) * WW;
        const int len = (x0 + 4 <= WW) ? 4 : (WW - x0);
        #pragma unroll
        for (int xo = 0; xo < 4; ++xo) {
            if (xo < len) {
                uint32_t lo = bf16rne(acc[xo][0]) | (bf16rne(acc[xo][1]) << 16);
                uint32_t hi = bf16rne(acc[xo][2]) | (bf16rne(acc[xo][3]) << 16);
                orow[x0 + xo] = make_uint2(lo, hi);
            }
        }
    }
}

// ---------------- Kernel 2: sequential LSTM, one block per batch image ----------------
// 1024 threads: thread owns a 6-px run (12 runs/row x 82 rows = 984 active)
__global__ __launch_bounds__(1024) void k_lstm(
    const uint2* __restrict__ xz, const float* __restrict__ wh,
    float* __restrict__ hout)
{
    __shared__ float hb[2][PIX];
    const int b = blockIdx.x;
    const int tid = threadIdx.x;
    float whr[9][4];
    #pragma unroll
    for (int k = 0; k < 9; ++k)
        #pragma unroll
        for (int g = 0; g < 4; ++g) whr[k][g] = wh[k * 4 + g];

    for (int i = tid; i < PIX; i += 1024) hb[0][i] = 0.f;

    const bool active = tid < 984;
    const int ry = tid / 12;
    const int x0 = (tid % 12) * 6;
    const int len = active ? ((x0 + 6 <= WW) ? 6 : (WW - x0)) : 0;
    float c[6];
    #pragma unroll
    for (int j = 0; j < 6; ++j) c[j] = 0.f;
    __syncthreads();

    #pragma unroll 1
    for (int t = 0; t < TT; ++t) {
        const int cur = t & 1;
        if (active) {
            float z[6][4];
            const uint2* zb = xz + ((size_t)b * TT + t) * PIX + ry * WW;
            #pragma unroll
            for (int j = 0; j < 6; ++j) {
                uint2 zp = zb[(x0 + j < WW) ? (x0 + j) : (WW - 1)];
                z[j][0] = bf16tof(zp.x); z[j][1] = bf16tof(zp.x >> 16);
                z[j][2] = bf16tof(zp.y); z[j][3] = bf16tof(zp.y >> 16);
            }
            #pragma unroll
            for (int ky = 0; ky < 3; ++ky) {
                int iy = ry + ky - 1;
                if (iy < 0 || iy >= HH) continue;
                const float* hr = &hb[cur][iy * WW];
                #pragma unroll
                for (int dx = -1; dx < 7; ++dx) {
                    int xi = x0 + dx;
                    if (xi < 0 || xi >= WW) continue;
                    float hv = hr[xi];
                    #pragma unroll
                    for (int kx = 0; kx < 3; ++kx) {
                        int xo = dx - kx + 1;
                        if (xo < 0 || xo > 5) continue;
                        #pragma unroll
                        for (int g = 0; g < 4; ++g)
                            z[xo][g] = fmaf(hv, whr[ky * 3 + kx][g], z[xo][g]);
                    }
                }
            }
            float* hw = &hb[cur ^ 1][ry * WW];
            #pragma unroll
            for (int j = 0; j < 6; ++j) {
                float fi = hsig(z[j][0]), ff = hsig(z[j][1]), fo = hsig(z[j][3]);
                float cn = ff * c[j] + fi * ftanh(z[j][2]);
                c[j] = cn;
                if (j < len) hw[x0 + j] = fo * ftanh(cn);
            }
        }
        __syncthreads();
    }
    for (int i = tid; i < PIX; i += 1024)
        hout[(size_t)b * PIX + i] = hb[0][i];
}

// ---------------- Kernel 3: conv1 5x5 s2 SAME, 6->64, +bias, LeakyReLU ----------------
// writes bf16 into padded x1p[64][45][37][64] at (y+2, x+1)
__global__ __launch_bounds__(256) void k_conv1(
    const float* __restrict__ hin, const float* __restrict__ tar,
    const float* __restrict__ w1, const float* __restrict__ b1,
    ushort* __restrict__ x1p)
{
    int wid = (blockIdx.x * 256 + threadIdx.x) >> 6;
    int lane = threadIdx.x & 63;
    int b = wid / 41, y = wid % 41;
    float acc[34];
    float bias = b1[lane];
    #pragma unroll
    for (int x = 0; x < 34; ++x) acc[x] = bias;
    #pragma unroll 1
    for (int ky = 0; ky < 5; ++ky) {
        int iy = 2 * y + ky - 1;
        if (iy < 0 || iy >= HH) continue;
        const float* hrow = hin + (size_t)b * PIX + iy * WW;
        const float* trow = tar + ((size_t)b * PIX + iy * WW) * 5;
        #pragma unroll 1
        for (int kx = 0; kx < 5; ++kx) {
            float w[6];
            #pragma unroll
            for (int ci = 0; ci < 6; ++ci)
                w[ci] = w1[((ky * 5 + kx) * 6 + ci) * 64 + lane];
            #pragma unroll
            for (int x = 0; x < 34; ++x) {
                int ix = 2 * x + kx - 2;
                if (ix < 0 || ix >= WW) continue;
                float v0 = hrow[ix];
                acc[x] += v0 * w[0];
                #pragma unroll
                for (int c = 0; c < 5; ++c)
                    acc[x] += trow[ix * 5 + c] * w[c + 1];
            }
        }
    }
    ushort* obase = x1p + ((size_t)(b * 45 + y + 2) * 37) * 64;
    #pragma unroll
    for (int x = 0; x < 34; ++x)
        obase[(x + 1) * 64 + lane] = (ushort)bf16rne(lrelu(acc[x]));
}

// ---------------- Weight transpose+cvt: wt[n][k] = bf16(w[k][n]) ----------------
__global__ __launch_bounds__(256) void k_wt(
    const float* __restrict__ w, ushort* __restrict__ wt, int K, int N)
{
    int idx = blockIdx.x * 256 + threadIdx.x;
    if (idx >= K * N) return;
    int n = idx / K, k = idx % K;
    wt[idx] = (ushort)bf16rne(w[(size_t)k * N + n]);
}

// ---------------- MFMA implicit-GEMM conv (conv2 / conv3) ----------------
// IS3=true : conv3  A=x2p[64][23][19][128], B=w3t[512][2048], out bf16 x3b[m][512] + BN + lrelu
// IS3=false: conv2  A=x1p[64][45][37][64],  B=w2t[128][1600], out bf16 into x2p(+1,+1) + bias + lrelu
template<bool IS3>
__global__ __launch_bounds__(256) void k_convm(
    const ushort* __restrict__ Ain, const ushort* __restrict__ Bt,
    const float* __restrict__ p0, const float* __restrict__ p1,
    const float* __restrict__ p2, const float* __restrict__ p3,
    ushort* __restrict__ outp)
{
    constexpr int OH = IS3 ? 20 : 21, OW = IS3 ? 16 : 17;
    constexpr int PH = IS3 ? 23 : 45, PW = IS3 ? 19 : 37;
    constexpr int CIN = IS3 ? 128 : 64;
    constexpr int KW_ = IS3 ? 4 : 5;
    constexpr int KK  = IS3 ? 16 : 25;
    constexpr int STR = IS3 ? 1 : 2;
    constexpr int HALVES = CIN / 64;
    constexpr int MPB = OH * OW;
    constexpr int M = 64 * MPB;
    constexpr int KTOT = KK * CIN;

    __shared__ ushort At[128 * 64];
    __shared__ ushort Bl[128 * 64];

    const int tid = threadIdx.x;
    const int wid = tid >> 6, lane = tid & 63;
    const int m0 = blockIdx.x * 128;
    const int n0 = blockIdx.y * 128;
    const int wr = wid >> 1, wc = wid & 1;

    const int swz = (((lane & 7) ^ ((lane >> 3) & 7)) << 3);

    int arow_base[4], brow_base[4];
    #pragma unroll
    for (int i = 0; i < 4; ++i) {
        int row = wid * 32 + i * 8 + (lane >> 3);
        int m = m0 + row; if (m > M - 1) m = M - 1;
        int b = m / MPB, r = m % MPB;
        int y = r / OW, x = r % OW;
        arow_base[i] = ((b * PH + y * STR) * PW + x * STR) * CIN;
        brow_base[i] = (n0 + row) * KTOT;
    }

    f32x4 acc[4][4];
    #pragma unroll
    for (int i = 0; i < 4; ++i)
        #pragma unroll
        for (int j = 0; j < 4; ++j) acc[i][j] = (f32x4){0.f, 0.f, 0.f, 0.f};

    #pragma unroll 1
    for (int kp = 0; kp < KK; ++kp) {
        const int ky = kp / KW_, kx = kp % KW_;
        const int aoff = (ky * PW + kx) * CIN;
        #pragma unroll
        for (int h = 0; h < HALVES; ++h) {
            const int koff = h * 64;
            #pragma unroll
            for (int i = 0; i < 4; ++i) {
                gload16(Ain + arow_base[i] + aoff + koff + swz,
                        (void*)(At + (wid * 32 + i * 8) * 64));
                gload16(Bt + brow_base[i] + kp * CIN + koff + swz,
                        (void*)(Bl + (wid * 32 + i * 8) * 64));
            }
            __syncthreads();
            #pragma unroll
            for (int ks = 0; ks < 2; ++ks) {
                short8 af[4], bf[4];
                const int lc = ks * 64 + ((lane >> 4) << 4);
                #pragma unroll
                for (int mf = 0; mf < 4; ++mf) {
                    int row = wr * 64 + mf * 16 + (lane & 15);
                    af[mf] = *(const short8*)((const char*)At + row * 128 + (lc ^ ((row & 7) << 4)));
                }
                #pragma unroll
                for (int nf = 0; nf < 4; ++nf) {
                    int row = wc * 64 + nf * 16 + (lane & 15);
                    bf[nf] = *(const short8*)((const char*)Bl + row * 128 + (lc ^ ((row & 7) << 4)));
                }
                #pragma unroll
                for (int mf = 0; mf < 4; ++mf)
                    #pragma unroll
                    for (int nf = 0; nf < 4; ++nf)
                        acc[mf][nf] = __builtin_amdgcn_mfma_f32_16x16x32_bf16(
                            af[mf], bf[nf], acc[mf][nf], 0, 0, 0);
            }
            __syncthreads();
        }
    }

    if (IS3) {
        #pragma unroll
        for (int nf = 0; nf < 4; ++nf) {
            int n = n0 + wc * 64 + nf * 16 + (lane & 15);
            float sc = p0[n] * rsqrtf(p3[n] + 1e-3f);
            float sh = p1[n] - p2[n] * sc;
            #pragma unroll
            for (int mf = 0; mf < 4; ++mf) {
                int mbase = m0 + wr * 64 + mf * 16 + ((lane >> 4) << 2);
                #pragma unroll
                for (int r = 0; r < 4; ++r) {
                    float v = lrelu(acc[mf][nf][r] * sc + sh);
                    outp[(size_t)(mbase + r) * 512 + n] = (ushort)bf16rne(v);
                }
            }
        }
    } else {
        #pragma unroll
        for (int nf = 0; nf < 4; ++nf) {
            int n = wc * 64 + nf * 16 + (lane & 15);
            float bias = p0[n];
            #pragma unroll
            for (int mf = 0; mf < 4; ++mf) {
                int mbase = m0 + wr * 64 + mf * 16 + ((lane >> 4) << 2);
                #pragma unroll
                for (int r = 0; r < 4; ++r) {
                    int m = mbase + r;
                    if (m < M) {
                        int b = m / MPB, rr = m % MPB;
                        int y = rr / OW, x = rr % OW;
                        float v = lrelu(acc[mf][nf][r] + bias);
                        outp[((size_t)((b * 23) + (y + 1)) * 19 + (x + 1)) * 128 + n] =
                            (ushort)bf16rne(v);
                    }
                }
            }
        }
    }
}

// ---------------- Kernel 6: pad1 + conv4 4x4 VALID, 512->1, +bias (bf16 in) ----------------
__global__ __launch_bounds__(64) void k_conv4(
    const ushort* __restrict__ x3, const float* __restrict__ w4,
    const float* __restrict__ b4, float* __restrict__ out)
{
    int b = blockIdx.x / 19, y = blockIdx.x % 19;
    int lane = threadIdx.x;
    int c0 = lane * 8;
    float acc[15];
    #pragma unroll
    for (int x = 0; x < 15; ++x) acc[x] = 0.f;
    #pragma unroll 1
    for (int ky = 0; ky < 4; ++ky) {
        int iy = y + ky - 1;
        if (iy < 0 || iy >= 20) continue;
        // weights for this ky, all 4 kx
        float w[4][8];
        #pragma unroll
        for (int kx = 0; kx < 4; ++kx) {
            const float4 wa = *(const float4*)(w4 + (ky * 4 + kx) * 512 + c0);
            const float4 wb = *(const float4*)(w4 + (ky * 4 + kx) * 512 + c0 + 4);
            w[kx][0] = wa.x; w[kx][1] = wa.y; w[kx][2] = wa.z; w[kx][3] = wa.w;
            w[kx][4] = wb.x; w[kx][5] = wb.y; w[kx][6] = wb.z; w[kx][7] = wb.w;
        }
        #pragma unroll 1
        for (int ix = 0; ix < 16; ++ix) {
            uint4 u = *(const uint4*)(x3 + ((size_t)(b * 20 + iy) * 16 + ix) * 512 + c0);
            float v[8];
            v[0] = bf16tof(u.x); v[1] = bf16tof(u.x >> 16);
            v[2] = bf16tof(u.y); v[3] = bf16tof(u.y >> 16);
            v[4] = bf16tof(u.z); v[5] = bf16tof(u.z >> 16);
            v[6] = bf16tof(u.w); v[7] = bf16tof(u.w >> 16);
            #pragma unroll
            for (int kx = 0; kx < 4; ++kx) {
                int x = ix - kx + 1;
                if (x < 0 || x > 14) continue;
                float s = 0.f;
                #pragma unroll
                for (int c = 0; c < 8; ++c) s = fmaf(v[c], w[kx][c], s);
                acc[x] += s;
            }
        }
    }
    float bias = b4[0];
    #pragma unroll
    for (int x = 0; x < 15; ++x) {
        float s = acc[x];
        #pragma unroll
        for (int off = 32; off > 0; off >>= 1)
            s += __shfl_down(s, off);
        if (lane == 0) out[(size_t)blockIdx.x * 15 + x] = s + bias;
    }
}

extern "C" void kernel_launch(void* const* d_in, const int* in_sizes, int n_in,
                              void* d_out, int out_size, void* d_ws, size_t ws_size,
                              hipStream_t stream)
{
    const float* inp  = (const float*)d_in[0];
    const float* tar  = (const float*)d_in[1];
    const float* wx   = (const float*)d_in[2];
    const float* wh   = (const float*)d_in[3];
    const float* bl   = (const float*)d_in[4];
    const float* w1   = (const float*)d_in[5];
    const float* b1   = (const float*)d_in[6];
    const float* w2   = (const float*)d_in[7];
    const float* b2   = (const float*)d_in[8];
    const float* w3   = (const float*)d_in[9];
    const float* gam  = (const float*)d_in[10];
    const float* bet  = (const float*)d_in[11];
    const float* mean = (const float*)d_in[12];
    const float* var  = (const float*)d_in[13];
    const float* w4   = (const float*)d_in[14];
    const float* b4   = (const float*)d_in[15];
    float* out = (float*)d_out;

    char* ws = (char*)d_ws;
    // xz: 67,510,272 B (dead after k_lstm); x3b bf16 20,971,520 B aliases it
    uint2*  xz   = (uint2*)(ws);
    ushort* x3b  = (ushort*)(ws);
    float*  hfin = (float*)(ws + 67510272);     // 1,406,464 B
    ushort* x1p  = (ushort*)(ws + 68916736);    // 13,639,680 B
    ushort* x2p  = (ushort*)(ws + 82556416);    // 7,159,808 B
    ushort* w2t  = (ushort*)(ws + 89716224);    // 409,600 B
    ushort* w3t  = (ushort*)(ws + 90125824);    // 2,097,152 B
    // total 92,222,976 B

    hipMemsetAsync(x1p, 0, 13639680, stream);
    hipMemsetAsync(x2p, 0, 7159808, stream);

    k_wt<<<(128 * 1600 + 255) / 256, 256, 0, stream>>>(w2, w2t, 1600, 128);
    k_wt<<<(512 * 2048 + 255) / 256, 256, 0, stream>>>(w3, w3t, 2048, 512);

    k_xz<<<1536 * 6, 256, 0, stream>>>(inp, wx, bl, xz);
    k_lstm<<<BB, 1024, 0, stream>>>(xz, wh, hfin);
    k_conv1<<<656, 256, 0, stream>>>(hfin, tar, w1, b1, x1p);

    dim3 g2(179, 1);
    k_convm<false><<<g2, 256, 0, stream>>>(x1p, w2t, b2, nullptr, nullptr, nullptr, x2p);
    dim3 g3(160, 4);
    k_convm<true><<<g3, 256, 0, stream>>>(x2p, w3t, gam, bet, mean, var, x3b);

    k_conv4<<<BB * 19, 64, 0, stream>>>(x3b, w4, b4, out);
}

// Round 4
// 475.942 us; speedup vs baseline: 7.4520x; 1.2076x over previous
//
#include <hip/hip_runtime.h>
#include <hip/hip_bf16.h>
#include <cstdint>

#define DEV static __device__ __forceinline__

typedef __attribute__((ext_vector_type(8))) short short8;
typedef __attribute__((ext_vector_type(4))) float f32x4;
typedef __attribute__((ext_vector_type(2))) float f32x2;

DEV uint32_t bf16rne(float f) {
    uint32_t u = __float_as_uint(f);
    uint32_t r = u + 0x7FFFu + ((u >> 16) & 1u);
    return r >> 16;
}
DEV float bf16tof(uint32_t h) { return __uint_as_float((h & 0xFFFFu) << 16); }
DEV float hsig(float z) { return fminf(fmaxf(0.2f * z + 0.5f, 0.f), 1.f); }
DEV float lrelu(float x) { return x >= 0.f ? x : 0.3f * x; }
DEV float ftanh(float x) {
    float e = __expf(2.0f * x);
    return 1.0f - 2.0f * __builtin_amdgcn_rcpf(e + 1.0f);
}

DEV void gload16(const void* g, void* l) {
    __builtin_amdgcn_global_load_lds(
        reinterpret_cast<const __attribute__((address_space(1))) uint32_t*>(
            reinterpret_cast<uintptr_t>(g)),
        reinterpret_cast<__attribute__((address_space(3))) uint32_t*>(
            reinterpret_cast<uintptr_t>(l)),
        16, 0, 0);
}

#define HH 82
#define WW 67
#define PIX (HH * WW)   // 5494
#define BB 64
#define TT 24

// ---------------- Kernel 1: xz = conv(x_t, wx) + b_lstm, register-tiled ----------------
// thread = 4-px run of one row. 17 runs/row, 82 rows, 1536 images.
__global__ __launch_bounds__(256) void k_xz(
    const float* __restrict__ inp, const float* __restrict__ wx,
    const float* __restrict__ bl, uint2* __restrict__ xz)
{
    const int g = blockIdx.x * 256 + threadIdx.x;
    const int run = g % 17;
    const int y   = (g / 17) % HH;
    const int bt  = g / (17 * HH);
    if (bt >= BB * TT) return;
    const int x0 = run * 4;
    const float* img = inp + (size_t)bt * (PIX * 6);

    f32x2 a01[4], a23[4];
    const f32x2 bias01 = {bl[0], bl[1]};
    const f32x2 bias23 = {bl[2], bl[3]};
    #pragma unroll
    for (int xo = 0; xo < 4; ++xo) { a01[xo] = bias01; a23[xo] = bias23; }

    #pragma unroll
    for (int r = 0; r < 3; ++r) {
        const int iy = y + r - 1;
        if (iy < 0 || iy >= HH) continue;

        // load 6 px x 6 ch of this row into registers (zero-padded at x edges)
        f32x2 v[6][3];
        #pragma unroll
        for (int p = 0; p < 6; ++p)
            #pragma unroll
            for (int c = 0; c < 3; ++c) v[p][c] = (f32x2){0.f, 0.f};

        const float* rp = img + (size_t)(iy * WW) * 6;
        if (run > 0) {
            const float* q = rp + (size_t)(x0 - 1) * 6;
            v[0][0] = *(const f32x2*)(q);
            v[0][1] = *(const f32x2*)(q + 2);
            v[0][2] = *(const f32x2*)(q + 4);
        }
        #pragma unroll
        for (int p = 1; p < 4; ++p) {
            const float* q = rp + (size_t)(x0 - 1 + p) * 6;
            v[p][0] = *(const f32x2*)(q);
            v[p][1] = *(const f32x2*)(q + 2);
            v[p][2] = *(const f32x2*)(q + 4);
        }
        if (run < 16) {
            #pragma unroll
            for (int p = 4; p < 6; ++p) {
                const float* q = rp + (size_t)(x0 - 1 + p) * 6;
                v[p][0] = *(const f32x2*)(q);
                v[p][1] = *(const f32x2*)(q + 2);
                v[p][2] = *(const f32x2*)(q + 4);
            }
        }

        // accumulate: taps (r, kx)
        #pragma unroll
        for (int kx = 0; kx < 3; ++kx) {
            const float* w6 = wx + (r * 3 + kx) * 24;
            #pragma unroll
            for (int ci = 0; ci < 6; ++ci) {
                const f32x2 w01 = *(const f32x2*)(w6 + ci * 4);
                const f32x2 w23 = *(const f32x2*)(w6 + ci * 4 + 2);
                #pragma unroll
                for (int xo = 0; xo < 4; ++xo) {
                    const float s = v[xo + kx][ci >> 1][ci & 1];
                    a01[xo] += s * w01;
                    a23[xo] += s * w23;
                }
            }
        }
    }

    uint2* orow = xz + ((size_t)bt * HH + y) * WW;
    uint32_t lo[4], hi[4];
    #pragma unroll
    for (int xo = 0; xo < 4; ++xo) {
        lo[xo] = bf16rne(a01[xo][0]) | (bf16rne(a01[xo][1]) << 16);
        hi[xo] = bf16rne(a23[xo][0]) | (bf16rne(a23[xo][1]) << 16);
    }
    if (run < 16) {
        *(uint4*)(orow + x0)     = make_uint4(lo[0], hi[0], lo[1], hi[1]);
        *(uint4*)(orow + x0 + 2) = make_uint4(lo[2], hi[2], lo[3], hi[3]);
    } else {
        orow[x0]     = make_uint2(lo[0], hi[0]);
        orow[x0 + 1] = make_uint2(lo[1], hi[1]);
        orow[x0 + 2] = make_uint2(lo[2], hi[2]);
    }
}

// ---------------- Kernel 2: sequential LSTM, one block per batch image ----------------
__global__ __launch_bounds__(1024) void k_lstm(
    const uint2* __restrict__ xz, const float* __restrict__ wh,
    float* __restrict__ hout)
{
    __shared__ float hb[2][PIX];
    const int b = blockIdx.x;
    const int tid = threadIdx.x;
    float whr[9][4];
    #pragma unroll
    for (int k = 0; k < 9; ++k)
        #pragma unroll
        for (int g = 0; g < 4; ++g) whr[k][g] = wh[k * 4 + g];

    for (int i = tid; i < PIX; i += 1024) hb[0][i] = 0.f;

    const bool active = tid < 984;
    const int ry = tid / 12;
    const int x0 = (tid % 12) * 6;
    const int len = active ? ((x0 + 6 <= WW) ? 6 : (WW - x0)) : 0;
    float c[6];
    #pragma unroll
    for (int j = 0; j < 6; ++j) c[j] = 0.f;
    __syncthreads();

    #pragma unroll 1
    for (int t = 0; t < TT; ++t) {
        const int cur = t & 1;
        if (active) {
            float z[6][4];
            const uint2* zb = xz + ((size_t)b * TT + t) * PIX + ry * WW;
            #pragma unroll
            for (int j = 0; j < 6; ++j) {
                uint2 zp = zb[(x0 + j < WW) ? (x0 + j) : (WW - 1)];
                z[j][0] = bf16tof(zp.x); z[j][1] = bf16tof(zp.x >> 16);
                z[j][2] = bf16tof(zp.y); z[j][3] = bf16tof(zp.y >> 16);
            }
            #pragma unroll
            for (int ky = 0; ky < 3; ++ky) {
                int iy = ry + ky - 1;
                if (iy < 0 || iy >= HH) continue;
                const float* hr = &hb[cur][iy * WW];
                #pragma unroll
                for (int dx = -1; dx < 7; ++dx) {
                    int xi = x0 + dx;
                    if (xi < 0 || xi >= WW) continue;
                    float hv = hr[xi];
                    #pragma unroll
                    for (int kx = 0; kx < 3; ++kx) {
                        int xo = dx - kx + 1;
                        if (xo < 0 || xo > 5) continue;
                        #pragma unroll
                        for (int g = 0; g < 4; ++g)
                            z[xo][g] = fmaf(hv, whr[ky * 3 + kx][g], z[xo][g]);
                    }
                }
            }
            float* hw = &hb[cur ^ 1][ry * WW];
            #pragma unroll
            for (int j = 0; j < 6; ++j) {
                float fi = hsig(z[j][0]), ff = hsig(z[j][1]), fo = hsig(z[j][3]);
                float cn = ff * c[j] + fi * ftanh(z[j][2]);
                c[j] = cn;
                if (j < len) hw[x0 + j] = fo * ftanh(cn);
            }
        }
        __syncthreads();
    }
    for (int i = tid; i < PIX; i += 1024)
        hout[(size_t)b * PIX + i] = hb[0][i];
}

// ---------------- Kernel 3: conv1 5x5 s2 SAME, 6->64, +bias, LeakyReLU ----------------
// writes bf16 into padded x1p[64][45][37][64] at (y+2, x+1)
__global__ __launch_bounds__(256) void k_conv1(
    const float* __restrict__ hin, const float* __restrict__ tar,
    const float* __restrict__ w1, const float* __restrict__ b1,
    ushort* __restrict__ x1p)
{
    int wid = (blockIdx.x * 256 + threadIdx.x) >> 6;
    int lane = threadIdx.x & 63;
    int b = wid / 41, y = wid % 41;
    float acc[34];
    float bias = b1[lane];
    #pragma unroll
    for (int x = 0; x < 34; ++x) acc[x] = bias;
    #pragma unroll 1
    for (int ky = 0; ky < 5; ++ky) {
        int iy = 2 * y + ky - 1;
        if (iy < 0 || iy >= HH) continue;
        const float* hrow = hin + (size_t)b * PIX + iy * WW;
        const float* trow = tar + ((size_t)b * PIX + iy * WW) * 5;
        #pragma unroll 1
        for (int kx = 0; kx < 5; ++kx) {
            float w[6];
            #pragma unroll
            for (int ci = 0; ci < 6; ++ci)
                w[ci] = w1[((ky * 5 + kx) * 6 + ci) * 64 + lane];
            #pragma unroll
            for (int x = 0; x < 34; ++x) {
                int ix = 2 * x + kx - 2;
                if (ix < 0 || ix >= WW) continue;
                float v0 = hrow[ix];
                acc[x] += v0 * w[0];
                #pragma unroll
                for (int c = 0; c < 5; ++c)
                    acc[x] += trow[ix * 5 + c] * w[c + 1];
            }
        }
    }
    ushort* obase = x1p + ((size_t)(b * 45 + y + 2) * 37) * 64;
    #pragma unroll
    for (int x = 0; x < 34; ++x)
        obase[(x + 1) * 64 + lane] = (ushort)bf16rne(lrelu(acc[x]));
}

// ---------------- Weight transpose+cvt: wt[n][k] = bf16(w[k][n]) ----------------
__global__ __launch_bounds__(256) void k_wt(
    const float* __restrict__ w, ushort* __restrict__ wt, int K, int N)
{
    int idx = blockIdx.x * 256 + threadIdx.x;
    if (idx >= K * N) return;
    int n = idx / K, k = idx % K;
    wt[idx] = (ushort)bf16rne(w[(size_t)k * N + n]);
}

// ---------------- MFMA implicit-GEMM conv (conv2 / conv3) ----------------
template<bool IS3>
__global__ __launch_bounds__(256) void k_convm(
    const ushort* __restrict__ Ain, const ushort* __restrict__ Bt,
    const float* __restrict__ p0, const float* __restrict__ p1,
    const float* __restrict__ p2, const float* __restrict__ p3,
    ushort* __restrict__ outp)
{
    constexpr int OH = IS3 ? 20 : 21, OW = IS3 ? 16 : 17;
    constexpr int PH = IS3 ? 23 : 45, PW = IS3 ? 19 : 37;
    constexpr int CIN = IS3 ? 128 : 64;
    constexpr int KW_ = IS3 ? 4 : 5;
    constexpr int KK  = IS3 ? 16 : 25;
    constexpr int STR = IS3 ? 1 : 2;
    constexpr int HALVES = CIN / 64;
    constexpr int MPB = OH * OW;
    constexpr int M = 64 * MPB;
    constexpr int KTOT = KK * CIN;

    __shared__ ushort At[128 * 64];
    __shared__ ushort Bl[128 * 64];

    const int tid = threadIdx.x;
    const int wid = tid >> 6, lane = tid & 63;
    const int m0 = blockIdx.x * 128;
    const int n0 = blockIdx.y * 128;
    const int wr = wid >> 1, wc = wid & 1;

    const int swz = (((lane & 7) ^ ((lane >> 3) & 7)) << 3);

    int arow_base[4], brow_base[4];
    #pragma unroll
    for (int i = 0; i < 4; ++i) {
        int row = wid * 32 + i * 8 + (lane >> 3);
        int m = m0 + row; if (m > M - 1) m = M - 1;
        int b = m / MPB, r = m % MPB;
        int y = r / OW, x = r % OW;
        arow_base[i] = ((b * PH + y * STR) * PW + x * STR) * CIN;
        brow_base[i] = (n0 + row) * KTOT;
    }

    f32x4 acc[4][4];
    #pragma unroll
    for (int i = 0; i < 4; ++i)
        #pragma unroll
        for (int j = 0; j < 4; ++j) acc[i][j] = (f32x4){0.f, 0.f, 0.f, 0.f};

    #pragma unroll 1
    for (int kp = 0; kp < KK; ++kp) {
        const int ky = kp / KW_, kx = kp % KW_;
        const int aoff = (ky * PW + kx) * CIN;
        #pragma unroll
        for (int h = 0; h < HALVES; ++h) {
            const int koff = h * 64;
            #pragma unroll
            for (int i = 0; i < 4; ++i) {
                gload16(Ain + arow_base[i] + aoff + koff + swz,
                        (void*)(At + (wid * 32 + i * 8) * 64));
                gload16(Bt + brow_base[i] + kp * CIN + koff + swz,
                        (void*)(Bl + (wid * 32 + i * 8) * 64));
            }
            __syncthreads();
            #pragma unroll
            for (int ks = 0; ks < 2; ++ks) {
                short8 af[4], bf[4];
                const int lc = ks * 64 + ((lane >> 4) << 4);
                #pragma unroll
                for (int mf = 0; mf < 4; ++mf) {
                    int row = wr * 64 + mf * 16 + (lane & 15);
                    af[mf] = *(const short8*)((const char*)At + row * 128 + (lc ^ ((row & 7) << 4)));
                }
                #pragma unroll
                for (int nf = 0; nf < 4; ++nf) {
                    int row = wc * 64 + nf * 16 + (lane & 15);
                    bf[nf] = *(const short8*)((const char*)Bl + row * 128 + (lc ^ ((row & 7) << 4)));
                }
                #pragma unroll
                for (int mf = 0; mf < 4; ++mf)
                    #pragma unroll
                    for (int nf = 0; nf < 4; ++nf)
                        acc[mf][nf] = __builtin_amdgcn_mfma_f32_16x16x32_bf16(
                            af[mf], bf[nf], acc[mf][nf], 0, 0, 0);
            }
            __syncthreads();
        }
    }

    if (IS3) {
        #pragma unroll
        for (int nf = 0; nf < 4; ++nf) {
            int n = n0 + wc * 64 + nf * 16 + (lane & 15);
            float sc = p0[n] * rsqrtf(p3[n] + 1e-3f);
            float sh = p1[n] - p2[n] * sc;
            #pragma unroll
            for (int mf = 0; mf < 4; ++mf) {
                int mbase = m0 + wr * 64 + mf * 16 + ((lane >> 4) << 2);
                #pragma unroll
                for (int r = 0; r < 4; ++r) {
                    float v = lrelu(acc[mf][nf][r] * sc + sh);
                    outp[(size_t)(mbase + r) * 512 + n] = (ushort)bf16rne(v);
                }
            }
        }
    } else {
        #pragma unroll
        for (int nf = 0; nf < 4; ++nf) {
            int n = wc * 64 + nf * 16 + (lane & 15);
            float bias = p0[n];
            #pragma unroll
            for (int mf = 0; mf < 4; ++mf) {
                int mbase = m0 + wr * 64 + mf * 16 + ((lane >> 4) << 2);
                #pragma unroll
                for (int r = 0; r < 4; ++r) {
                    int m = mbase + r;
                    if (m < M) {
                        int b = m / MPB, rr = m % MPB;
                        int y = rr / OW, x = rr % OW;
                        float v = lrelu(acc[mf][nf][r] + bias);
                        outp[((size_t)((b * 23) + (y + 1)) * 19 + (x + 1)) * 128 + n] =
                            (ushort)bf16rne(v);
                    }
                }
            }
        }
    }
}

// ---------------- Kernel 6: pad1 + conv4 4x4 VALID, 512->1, +bias (bf16 in) ----------------
__global__ __launch_bounds__(64) void k_conv4(
    const ushort* __restrict__ x3, const float* __restrict__ w4,
    const float* __restrict__ b4, float* __restrict__ out)
{
    int b = blockIdx.x / 19, y = blockIdx.x % 19;
    int lane = threadIdx.x;
    int c0 = lane * 8;
    float acc[15];
    #pragma unroll
    for (int x = 0; x < 15; ++x) acc[x] = 0.f;
    #pragma unroll 1
    for (int ky = 0; ky < 4; ++ky) {
        int iy = y + ky - 1;
        if (iy < 0 || iy >= 20) continue;
        float w[4][8];
        #pragma unroll
        for (int kx = 0; kx < 4; ++kx) {
            const float4 wa = *(const float4*)(w4 + (ky * 4 + kx) * 512 + c0);
            const float4 wb = *(const float4*)(w4 + (ky * 4 + kx) * 512 + c0 + 4);
            w[kx][0] = wa.x; w[kx][1] = wa.y; w[kx][2] = wa.z; w[kx][3] = wa.w;
            w[kx][4] = wb.x; w[kx][5] = wb.y; w[kx][6] = wb.z; w[kx][7] = wb.w;
        }
        #pragma unroll 1
        for (int ix = 0; ix < 16; ++ix) {
            uint4 u = *(const uint4*)(x3 + ((size_t)(b * 20 + iy) * 16 + ix) * 512 + c0);
            float v[8];
            v[0] = bf16tof(u.x); v[1] = bf16tof(u.x >> 16);
            v[2] = bf16tof(u.y); v[3] = bf16tof(u.y >> 16);
            v[4] = bf16tof(u.z); v[5] = bf16tof(u.z >> 16);
            v[6] = bf16tof(u.w); v[7] = bf16tof(u.w >> 16);
            #pragma unroll
            for (int kx = 0; kx < 4; ++kx) {
                int x = ix - kx + 1;
                if (x < 0 || x > 14) continue;
                float s = 0.f;
                #pragma unroll
                for (int c = 0; c < 8; ++c) s = fmaf(v[c], w[kx][c], s);
                acc[x] += s;
            }
        }
    }
    float bias = b4[0];
    #pragma unroll
    for (int x = 0; x < 15; ++x) {
        float s = acc[x];
        #pragma unroll
        for (int off = 32; off > 0; off >>= 1)
            s += __shfl_down(s, off);
        if (lane == 0) out[(size_t)blockIdx.x * 15 + x] = s + bias;
    }
}

extern "C" void kernel_launch(void* const* d_in, const int* in_sizes, int n_in,
                              void* d_out, int out_size, void* d_ws, size_t ws_size,
                              hipStream_t stream)
{
    const float* inp  = (const float*)d_in[0];
    const float* tar  = (const float*)d_in[1];
    const float* wx   = (const float*)d_in[2];
    const float* wh   = (const float*)d_in[3];
    const float* bl   = (const float*)d_in[4];
    const float* w1   = (const float*)d_in[5];
    const float* b1   = (const float*)d_in[6];
    const float* w2   = (const float*)d_in[7];
    const float* b2   = (const float*)d_in[8];
    const float* w3   = (const float*)d_in[9];
    const float* gam  = (const float*)d_in[10];
    const float* bet  = (const float*)d_in[11];
    const float* mean = (const float*)d_in[12];
    const float* var  = (const float*)d_in[13];
    const float* w4   = (const float*)d_in[14];
    const float* b4   = (const float*)d_in[15];
    float* out = (float*)d_out;

    char* ws = (char*)d_ws;
    uint2*  xz   = (uint2*)(ws);
    ushort* x3b  = (ushort*)(ws);
    float*  hfin = (float*)(ws + 67510272);
    ushort* x1p  = (ushort*)(ws + 68916736);
    ushort* x2p  = (ushort*)(ws + 82556416);
    ushort* w2t  = (ushort*)(ws + 89716224);
    ushort* w3t  = (ushort*)(ws + 90125824);

    hipMemsetAsync(x1p, 0, 13639680, stream);
    hipMemsetAsync(x2p, 0, 7159808, stream);

    k_wt<<<(128 * 1600 + 255) / 256, 256, 0, stream>>>(w2, w2t, 1600, 128);
    k_wt<<<(512 * 2048 + 255) / 256, 256, 0, stream>>>(w3, w3t, 2048, 512);

    const int nthreads = BB * TT * HH * 17;
    k_xz<<<(nthreads + 255) / 256, 256, 0, stream>>>(inp, wx, bl, xz);
    k_lstm<<<BB, 1024, 0, stream>>>(xz, wh, hfin);
    k_conv1<<<656, 256, 0, stream>>>(hfin, tar, w1, b1, x1p);

    dim3 g2(179, 1);
    k_convm<false><<<g2, 256, 0, stream>>>(x1p, w2t, b2, nullptr, nullptr, nullptr, x2p);
    dim3 g3(160, 4);
    k_convm<true><<<g3, 256, 0, stream>>>(x2p, w3t, gam, bet, mean, var, x3b);

    k_conv4<<<BB * 19, 64, 0, stream>>>(x3b, w4, b4, out);
}